// Round 8
// baseline (138.510 us; speedup 1.0000x reference)
//
#include <hip/hip_runtime.h>
#include <hip/hip_bf16.h>

#define QUERY_DIM 128
#define HIDDEN 128

typedef float f32x4 __attribute__((ext_vector_type(4)));

__device__ __forceinline__ float dot4(f32x4 a, f32x4 b) {
    return a.x * b.x + a.y * b.y + a.z * b.z + a.w * b.w;
}

// ---------------------------------------------------------------------------
// Kernel 1 (combo): blocks 0..63  -> W[e][d] = sum_h WQ[h][e]*WK[h][d]
//                   blocks 64..   -> segment starts via binary search
// ---------------------------------------------------------------------------
__global__ __launch_bounds__(256) void combo_kernel(const float* __restrict__ WQ,
                                                    const float* __restrict__ WK,
                                                    float* __restrict__ W,
                                                    const int* __restrict__ idx,
                                                    int* __restrict__ start,
                                                    int nmols, int total) {
    int b = blockIdx.x;
    int t = threadIdx.x;
    if (b < 64) {
        int e = b * 2 + (t >> 7);   // 0..127
        int d = t & 127;
        float acc = 0.f;
#pragma unroll 8
        for (int h = 0; h < HIDDEN; ++h) {
            acc += WQ[h * QUERY_DIM + e] * WK[h * 128 + d];
        }
        W[e * 128 + d] = acc;
    } else {
        int m = (b - 64) * 256 + t;
        if (m > nmols) return;
        if (m == nmols) { start[m] = total; return; }
        int lo = 0, hi = total;
        while (lo < hi) {
            int mid = (lo + hi) >> 1;
            if (idx[mid] < m) lo = mid + 1; else hi = mid;
        }
        start[m] = lo;
    }
}

// ---------------------------------------------------------------------------
// Kernel 2: R = query @ W.  16 rows/block, 256 threads, d tiled by 4.
// ---------------------------------------------------------------------------
__global__ __launch_bounds__(256) void qproj_kernel(const float* __restrict__ Q,
                                                    const float* __restrict__ W,
                                                    float* __restrict__ R, int nmols) {
    __shared__ float wl[64 * 128];  // 32 KB (half of W)
    __shared__ float ql[16 * 128];  // 8 KB (16 query rows)
    int t = threadIdx.x;
    int c = t & 127;
    int g = t >> 7;
    long row0 = (long)blockIdx.x * 16;

    for (int i = t * 4; i < 16 * 128; i += 256 * 4) {
        *(float4*)&ql[i] = *(const float4*)&Q[row0 * QUERY_DIM + i];
    }

    float acc[8] = {0.f, 0.f, 0.f, 0.f, 0.f, 0.f, 0.f, 0.f};

    for (int half = 0; half < 2; ++half) {
        __syncthreads();
        for (int i = t * 4; i < 64 * 128; i += 256 * 4) {
            *(float4*)&wl[i] = *(const float4*)&W[half * 64 * 128 + i];
        }
        __syncthreads();
        for (int d = 0; d < 64; d += 4) {
            float w0 = wl[(d + 0) * 128 + c];
            float w1 = wl[(d + 1) * 128 + c];
            float w2 = wl[(d + 2) * 128 + c];
            float w3 = wl[(d + 3) * 128 + c];
            int dg = half * 64 + d;
#pragma unroll
            for (int r = 0; r < 8; ++r) {
                f32x4 q = *(const f32x4*)&ql[(g * 8 + r) * 128 + dg];
                acc[r] += q.x * w0 + q.y * w1 + q.z * w2 + q.w * w3;
            }
        }
    }
#pragma unroll
    for (int r = 0; r < 8; ++r) {
        long row = row0 + g * 8 + r;
        if (row < nmols) R[row * 128 + c] = acc[r];
    }
}

// ---------------------------------------------------------------------------
// Kernel 3 (fused, dominant): per segment scores + ONLINE softmax.
// wave w -> segments 2w, 2w+1 (consecutive): each wave streams a contiguous
// ~128KB K region; adjacent waves stream adjacent regions (DRAM page +
// L2/XCD locality). Phase 1: double-buffered 8-key batches (8 x 1KB loads in
// flight), online max+sum in registers (no phase-2 pass). Phase 3: weights
// from L1-hot scores re-read after a single per-segment vmcnt drain.
// ---------------------------------------------------------------------------
__global__ __launch_bounds__(256) void fused_kernel(const float* __restrict__ K,
                                                    const float* __restrict__ R,
                                                    const int* __restrict__ start,
                                                    float* __restrict__ weights,
                                                    float* scores,   // no restrict: store+load alias
                                                    int nmols) {
    const int lane = threadIdx.x & 63;
    const int half = lane >> 5;      // 0/1
    const int hl = lane & 31;        // lane within half-wave
    const int wave = (blockIdx.x * 256 + threadIdx.x) >> 6;   // 0..8191
    const float sc = 0.08838834764831845f;  // 1/sqrt(128)

    for (int si = 0; si < 2; ++si) {
        int s = wave * 2 + si;
        if (s >= nmols) break;
        int s0 = start[s], s1 = start[s + 1];
        if (s0 >= s1) continue;

        f32x4 rfrag = *((const f32x4*)(R + (long)s * 128) + hl);

        float mx = -__builtin_inff();
        float sum = 0.f;
        int kb = s0;

        // ---- phase 1: double-buffered 8-key batches, online max/sum ----
        f32x4 a0, a1, a2, a3;
        bool have = (kb + 8 <= s1);
        if (have) {
            long k = kb + half;                    // rows k, k+2, k+4, k+6
            a0 = __builtin_nontemporal_load((const f32x4*)(K + (k + 0) * 128) + hl);
            a1 = __builtin_nontemporal_load((const f32x4*)(K + (k + 2) * 128) + hl);
            a2 = __builtin_nontemporal_load((const f32x4*)(K + (k + 4) * 128) + hl);
            a3 = __builtin_nontemporal_load((const f32x4*)(K + (k + 6) * 128) + hl);
        }
        while (have) {
            bool havenext = (kb + 16 <= s1);
            f32x4 b0, b1, b2, b3;
            if (havenext) {                        // issue next batch NOW
                long kn = kb + 8 + half;
                b0 = __builtin_nontemporal_load((const f32x4*)(K + (kn + 0) * 128) + hl);
                b1 = __builtin_nontemporal_load((const f32x4*)(K + (kn + 2) * 128) + hl);
                b2 = __builtin_nontemporal_load((const f32x4*)(K + (kn + 4) * 128) + hl);
                b3 = __builtin_nontemporal_load((const f32x4*)(K + (kn + 6) * 128) + hl);
            }
            float v0 = dot4(a0, rfrag);
            float v1 = dot4(a1, rfrag);
            float v2 = dot4(a2, rfrag);
            float v3 = dot4(a3, rfrag);
#pragma unroll
            for (int off = 16; off > 0; off >>= 1) {
                v0 += __shfl_xor(v0, off, 64);
                v1 += __shfl_xor(v1, off, 64);
                v2 += __shfl_xor(v2, off, 64);
                v3 += __shfl_xor(v3, off, 64);
            }
            v0 *= sc; v1 *= sc; v2 *= sc; v3 *= sc;
            long k = kb + half;
            if (hl == 0) {
                scores[k + 0] = v0;
                scores[k + 2] = v1;
                scores[k + 4] = v2;
                scores[k + 6] = v3;
            }
            // online softmax update (mx=-inf safe: exp(-inf-finite)=0)
            float bm = fmaxf(fmaxf(v0, v1), fmaxf(v2, v3));
            float nm = fmaxf(mx, bm);
            sum = sum * __expf(mx - nm)
                + __expf(v0 - nm) + __expf(v1 - nm)
                + __expf(v2 - nm) + __expf(v3 - nm);
            mx = nm;
            kb += 8;
            a0 = b0; a1 = b1; a2 = b2; a3 = b3;
            have = havenext;
        }
        // tail (<8 keys): half h covers rows kb+h, kb+h+2, ...
        for (long k = kb + half; k < s1; k += 2) {
            f32x4 kv = __builtin_nontemporal_load((const f32x4*)(K + k * 128) + hl);
            float v = dot4(kv, rfrag);
#pragma unroll
            for (int off = 16; off > 0; off >>= 1) v += __shfl_xor(v, off, 64);
            v *= sc;
            if (hl == 0) scores[k] = v;
            float nm = fmaxf(mx, v);
            sum = sum * __expf(mx - nm) + __expf(v - nm);
            mx = nm;
        }
        // combine the two halves' (mx,sum)
        float mo = __shfl_xor(mx, 32, 64);
        float so = __shfl_xor(sum, 32, 64);
        float nm = fmaxf(mx, mo);
        sum = sum * __expf(mx - nm) + so * __expf(mo - nm);
        mx = nm;
        float inv = 1.0f / sum;

        // make this wave's score stores visible before re-reading
        asm volatile("s_waitcnt vmcnt(0)" ::: "memory");

        // ---- phase 3: weights from L1-hot scores ----
        for (int i = s0 + lane; i < s1; i += 64)
            weights[i] = __expf(scores[i] - mx) * inv;
    }
}

// ---------------------------------------------------------------------------
extern "C" void kernel_launch(void* const* d_in, const int* in_sizes, int n_in,
                              void* d_out, int out_size, void* d_ws, size_t ws_size,
                              hipStream_t stream) {
    const float* Q   = (const float*)d_in[0];
    const float* K   = (const float*)d_in[1];
    const float* WQ  = (const float*)d_in[2];
    const float* WK  = (const float*)d_in[3];
    const int*   idx = (const int*)d_in[4];

    const int nmols = in_sizes[0] / QUERY_DIM;   // 16384
    const int total = in_sizes[4];               // 1048576

    float* weights = (float*)d_out;              // output 0
    float* scores  = (float*)d_out + total;      // output 1

    char* ws = (char*)d_ws;
    float* W        = (float*)ws;                        // 64 KB
    int*   segstart = (int*)(ws + 65536);                // (nmols+1)*4
    float* R        = (float*)(ws + 65536 + 131072);     // nmols*128*4 = 8 MB

    int segblocks = (nmols + 1 + 255) / 256;
    combo_kernel<<<64 + segblocks, 256, 0, stream>>>(WQ, WK, W, idx, segstart, nmols, total);
    qproj_kernel<<<(nmols + 15) / 16, 256, 0, stream>>>(Q, W, R, nmols);
    // waves = 2048*256/64 = 8192; wave w owns segments 2w, 2w+1 (16384 total)
    fused_kernel<<<2048, 256, 0, stream>>>(K, R, segstart, weights, scores, nmols);
}